// Round 1
// baseline (536.656 us; speedup 1.0000x reference)
//
#include <hip/hip_runtime.h>
#include <math.h>

// DiffDispatchLP: batched (256x) PDHG solver, 400 iterations, LP with
// N=480 vars, M=2480 rows (97 equalities first, then inequalities, last
// row = total-charge with 96 nnz). One workgroup per batch item; all
// state in LDS/registers; sparse structure decoded analytically and held
// in registers (CSR: 10 rows x 4 entries/thread; CSC: 2 cols x 16/thread).

#define TT 96
#define NV 480
#define MROWS 2480
#define MEQ 97
#define TCROW 2479
#define NITER 400
#define PITER 40
#define YPAD 2736  // 2480 real + 256 dummy slots for padded rows

// Decode row r (0..2478) of K: up to 4 (col, val) entries + rhs kb.
// Row order matches the reference _build_lp exactly (A first, then G).
__device__ __forceinline__ void fill_row(int r, int* cols, float* vals, float* kb,
                                         float cET, float cDE) {
  float b = 0.0f;
  if (r < MEQ) {
    // equalities: soc dynamics
    if (r == 96) { cols[0] = 4*TT + 95; vals[0] = 1.0f; }
    else if (r == 0) {
      cols[0] = 4*TT;  vals[0] = 1.0f;
      cols[1] = 0;     vals[1] = cET;   // -ETA*DT * c_0
      cols[2] = TT;    vals[2] = cDE;   // +DT/ETA * d_0
    } else {
      int t = r;
      cols[0] = 4*TT + t;     vals[0] = 1.0f;
      cols[1] = 4*TT + t - 1; vals[1] = -1.0f;
      cols[2] = t;            vals[2] = cET;
      cols[3] = TT + t;       vals[3] = cDE;
    }
  } else if (r < 1345) {
    // 13 per-t box/logic rows
    int u = r - 97, t = u / 13, j = u - 13 * t;
    switch (j) {
      case 0:  cols[0] = t;        vals[0] = 1.f;  b = 195.f; break;
      case 1:  cols[0] = TT + t;   vals[0] = 1.f;  b = 195.f; break;
      case 2:  cols[0] = t;        vals[0] = -1.f; break;
      case 3:  cols[0] = TT + t;   vals[0] = -1.f; break;
      case 4:  cols[0] = 2*TT + t; vals[0] = -1.f; break;
      case 5:  cols[0] = 2*TT + t; vals[0] = 1.f;  b = 1.f; break;
      case 6:  cols[0] = 3*TT + t; vals[0] = -1.f; break;
      case 7:  cols[0] = 3*TT + t; vals[0] = 1.f;  b = 1.f; break;
      case 8:  cols[0] = 4*TT + t; vals[0] = -1.f; break;
      case 9:  cols[0] = 4*TT + t; vals[0] = 1.f;  b = 800.f; break;
      case 10: cols[0] = 2*TT + t; vals[0] = 1.f; cols[1] = 3*TT + t; vals[1] = 1.f; b = 1.f; break;
      case 11: cols[0] = t;        vals[0] = 1.f; cols[1] = 2*TT + t; vals[1] = -195.f; break;
      default: cols[0] = TT + t;   vals[0] = 1.f; cols[1] = 3*TT + t; vals[1] = -195.f; break;
    }
  } else if (r < 1725) {
    // ramps, t = 1..95, order [c up, c down, d up, d down]
    int u = r - 1345, t = 1 + u / 4, j = u & 3;
    int base = (j >= 2) ? TT : 0;
    if ((j & 1) == 0) { cols[0] = base + t;     vals[0] = 1.f; cols[1] = base + t - 1; vals[1] = -1.f; }
    else              { cols[0] = base + t - 1; vals[0] = 1.f; cols[1] = base + t;     vals[1] = -1.f; }
    b = 65.f;
  } else if (r < 1915) {
    // switch rows, t = 0..94
    int u = r - 1725, t = u >> 1, j = u & 1;
    if (j == 0) { cols[0] = 2*TT + t; vals[0] = 1.f; cols[1] = 3*TT + t + 1; vals[1] = 1.f; }
    else        { cols[0] = 3*TT + t; vals[0] = 1.f; cols[1] = 2*TT + t + 1; vals[1] = 1.f; }
    b = 1.f;
  } else {
    // min-duration, v-major (yc then yd), 282 rows each
    int u = r - 1915, vv = u / 282, m = u - 282 * vv;
    int base = (vv == 0) ? (2*TT) : (3*TT);
    int t, k;
    if (m < 279)      { t = m / 3; k = m - 3 * t + 1; }
    else if (m < 281) { t = 93;    k = m - 278; }
    else              { t = 94;    k = 1; }
    if (t == 0) { cols[0] = base + k; vals[0] = -1.f; cols[1] = base; vals[1] = 1.f; }
    else {
      cols[0] = base + t + k; vals[0] = -1.f;
      cols[1] = base + t;     vals[1] = 1.f;
      cols[2] = base + t - 1; vals[2] = -1.f;
    }
  }
  *kb = b;
}

__global__ __launch_bounds__(256, 1)
void lp_solve_kernel(const float* __restrict__ price, float* __restrict__ out) {
  __shared__ float          s_cscv[NV * 16];   // 30720 B
  __shared__ unsigned short s_cscr[NV * 16];   // 15360 B
  __shared__ int            s_cnt[NV];         //  1920 B
  __shared__ float          sy[YPAD];          // 10944 B (duals / power w)
  __shared__ float          sxb[NV];           //  1920 B (x_bar / power v)
  __shared__ float          s_red[4];

  const int tid = threadIdx.x;
  const int b   = blockIdx.x;

  const double ETA_D = sqrt(0.91);
  const float  cET = (float)(-(ETA_D * 0.25));  // matches np f32 cast of -ETA*DT
  const float  cDE = (float)(0.25 / ETA_D);

  // ---- per-thread CSR rows: r = tid + 256*j, j=0..9 (row 2479 excluded) ----
  int   rc[10][4];
  float rv[10][4];
  float rkb[10];
  int   ryt[10];   // LDS write target for the dual (dummy rows -> 2480+tid)
#pragma unroll
  for (int j = 0; j < 10; ++j) {
    int r = tid + 256 * j;
    int cols[4] = {0, 0, 0, 0};
    float vals[4] = {0.f, 0.f, 0.f, 0.f};
    float kb = 0.f;
    if (r < TCROW) fill_row(r, cols, vals, &kb, cET, cDE);
#pragma unroll
    for (int e = 0; e < 4; ++e) { rc[j][e] = cols[e]; rv[j][e] = vals[e]; }
    rkb[j] = (r < TCROW) ? kb : 0.f;
    ryt[j] = (r < TCROW) ? r : (2480 + tid);
  }

  // ---- build CSC (K^T) in LDS via atomic scatter; max col degree = 15 ----
  for (int i = tid; i < NV; i += 256) s_cnt[i] = 0;
  for (int i = tid; i < NV * 16; i += 256) { s_cscr[i] = 0; s_cscv[i] = 0.f; }
  __syncthreads();
#pragma unroll
  for (int j = 0; j < 10; ++j) {
    int r = tid + 256 * j;
    if (r < TCROW) {
#pragma unroll
      for (int e = 0; e < 4; ++e) {
        float v = rv[j][e];
        if (v != 0.f) {
          int c = rc[j][e];
          int p = atomicAdd(&s_cnt[c], 1);
          s_cscr[c * 16 + p] = (unsigned short)r;
          s_cscv[c * 16 + p] = v;
        }
      }
    }
  }
  if (tid < TT) {  // total-charge row touches every c_t with coeff DT
    int p = atomicAdd(&s_cnt[tid], 1);
    s_cscr[tid * 16 + p] = (unsigned short)TCROW;
    s_cscv[tid * 16 + p] = 0.25f;
  }
  __syncthreads();

  // ---- my 2 columns (n = tid, tid+256) into registers ----
  int   gr[2][16];
  float gv[2][16];
#pragma unroll
  for (int c2 = 0; c2 < 2; ++c2) {
    int c = tid + 256 * c2;
#pragma unroll
    for (int e = 0; e < 16; ++e) {
      if (c < NV) { gr[c2][e] = s_cscr[c * 16 + e]; gv[c2][e] = s_cscv[c * 16 + e]; }
      else        { gr[c2][e] = 0;                  gv[c2][e] = 0.f; }
    }
  }

  // ---- power iteration on K^T K for ||K||_2 (TAU = SIG = 0.9/L) ----
  for (int i = tid; i < NV; i += 256) sxb[i] = 1.0f;
  __syncthreads();
  float lam2 = 1.0f;
  for (int pit = 0; pit < PITER; ++pit) {
    // w = K v
#pragma unroll
    for (int j = 0; j < 10; ++j) {
      float s = 0.f;
#pragma unroll
      for (int e = 0; e < 4; ++e) s += rv[j][e] * sxb[rc[j][e]];
      sy[ryt[j]] = s;
    }
    if (tid < 64) {
      float s = sxb[tid] + ((tid < 32) ? sxb[64 + tid] : 0.f);
#pragma unroll
      for (int m = 32; m >= 1; m >>= 1) s += __shfl_xor(s, m, 64);
      if (tid == 0) sy[TCROW] = 0.25f * s;
    }
    __syncthreads();
    // v' = K^T w, norm via block reduction
    float nv0 = 0.f, nv1 = 0.f;
#pragma unroll
    for (int e = 0; e < 16; ++e) nv0 += gv[0][e] * sy[gr[0][e]];
#pragma unroll
    for (int e = 0; e < 16; ++e) nv1 += gv[1][e] * sy[gr[1][e]];
    float part = nv0 * nv0 + nv1 * nv1;
#pragma unroll
    for (int m = 32; m >= 1; m >>= 1) part += __shfl_xor(part, m, 64);
    if ((tid & 63) == 0) s_red[tid >> 6] = part;
    __syncthreads();
    float nrm2 = s_red[0] + s_red[1] + s_red[2] + s_red[3];
    lam2 = sqrtf(nrm2);            // ||K^T K v|| -> lambda_max^2 estimate
    float inv = 1.0f / lam2;
    sxb[tid] = nv0 * inv;
    if (tid < NV - 256) sxb[tid + 256] = nv1 * inv;
    __syncthreads();
  }
  const float tau = (float)(0.9 / sqrt((double)lam2));
  const float sig = tau;

  // ---- init PDHG state ----
  for (int i = tid; i < YPAD; i += 256) sy[i] = 0.f;
  float q1;
  if (tid < 96)       q1 =  0.25f * price[b * 96 + tid];
  else if (tid < 192) q1 = -0.25f * price[b * 96 + (tid - 96)];
  else                q1 = 0.f;   // q is 0 for yc/yd/soc (cols >= 192, incl. tid+256)
  float x1 = 0.f, x2 = 0.f;
  float yreg[10];
#pragma unroll
  for (int j = 0; j < 10; ++j) yreg[j] = 0.f;
  __syncthreads();

  // ---- 400 PDHG iterations ----
#pragma unroll 1
  for (int it = 0; it < NITER; ++it) {
    // phase A: x_new = x - tau*(q + K^T y); x_bar = 2 x_new - x
    float g1 = q1, g2 = 0.f;
#pragma unroll
    for (int e = 0; e < 16; ++e) g1 += gv[0][e] * sy[gr[0][e]];
#pragma unroll
    for (int e = 0; e < 16; ++e) g2 += gv[1][e] * sy[gr[1][e]];
    float xn1 = x1 - tau * g1;
    sxb[tid] = 2.f * xn1 - x1;
    x1 = xn1;
    if (tid < NV - 256) {
      float xn2 = x2 - tau * g2;
      sxb[tid + 256] = 2.f * xn2 - x2;
      x2 = xn2;
    }
    __syncthreads();
    // phase B: y += sig*(K x_bar - kb); project ineq duals >= 0
    if (tid < 64) {  // total-charge row: DT * sum(c_bar) <= 1200
      float s = sxb[tid] + ((tid < 32) ? sxb[64 + tid] : 0.f);
#pragma unroll
      for (int m = 32; m >= 1; m >>= 1) s += __shfl_xor(s, m, 64);
      if (tid == 0) {
        float yn = sy[TCROW] + sig * (0.25f * s - 1200.f);
        sy[TCROW] = fmaxf(yn, 0.f);
      }
    }
#pragma unroll
    for (int j = 0; j < 10; ++j) {
      float a = -rkb[j];
#pragma unroll
      for (int e = 0; e < 4; ++e) a += rv[j][e] * sxb[rc[j][e]];
      float yn = yreg[j] + sig * a;
      bool is_eq = (j == 0) && (tid < MEQ);  // rows 0..96 are equalities
      if (!is_eq) yn = fmaxf(yn, 0.f);
      yreg[j] = yn;
      sy[ryt[j]] = yn;
    }
    __syncthreads();
  }

  // ---- output: c = x[0:96], d = x[96:192]; out = [c (256x96), d (256x96)] ----
  if (tid < 96)       out[b * 96 + tid] = x1;
  else if (tid < 192) out[256 * 96 + b * 96 + (tid - 96)] = x1;
}

extern "C" void kernel_launch(void* const* d_in, const int* in_sizes, int n_in,
                              void* d_out, int out_size, void* d_ws, size_t ws_size,
                              hipStream_t stream) {
  const float* price = (const float*)d_in[0];
  float* out = (float*)d_out;
  hipLaunchKernelGGL(lp_solve_kernel, dim3(256), dim3(256), 0, stream, price, out);
}